// Round 6
// baseline (159.863 us; speedup 1.0000x reference)
//
#include <hip/hip_runtime.h>

#define IMG   384
#define NIMG  64
#define RWV   12                // valid rows per wave
#define RL    (RWV + 10)        // 22 loaded rows (5-row halo each side)
#define NW    4                 // independent waves per block
#define VX    116               // valid cols per tile
#define GRIDX 4                 // 3*116 + 36 = 384
#define GRIDY 8                 // 8 * (4*12) = 384 exact
#define NPART (GRIDX*GRIDY*NIMG*NW)   // one partial per wave = 8192

typedef float f32x2 __attribute__((ext_vector_type(2)));

static __device__ __forceinline__ f32x2 pk_add(f32x2 a, f32x2 b) {
    f32x2 d; asm("v_pk_add_f32 %0, %1, %2" : "=v"(d) : "v"(a), "v"(b)); return d;
}
// d.lo = a.lo + b.hi ; d.hi = a.hi + b.lo   (within-pair horizontal terms)
static __device__ __forceinline__ f32x2 pk_add_swap(f32x2 a, f32x2 b) {
    f32x2 d; asm("v_pk_add_f32 %0, %1, %2 op_sel:[0,1] op_sel_hi:[1,0]"
                 : "=v"(d) : "v"(a), "v"(b)); return d;
}
static __device__ __forceinline__ f32x2 pk_mul(f32x2 a, f32x2 b) {
    f32x2 d; asm("v_pk_mul_f32 %0, %1, %2" : "=v"(d) : "v"(a), "v"(b)); return d;
}
// lane i <- lane i-1, lane 0 gets 0 (WAVE_SHR1)
static __device__ __forceinline__ float dpp_sr1(float x) {
    return __int_as_float(
        __builtin_amdgcn_update_dpp(0, __float_as_int(x), 0x138, 0xF, 0xF, true));
}
// lane i <- lane i+1, lane 63 gets 0 (WAVE_SHL1)
static __device__ __forceinline__ float dpp_sl1(float x) {
    return __int_as_float(
        __builtin_amdgcn_update_dpp(0, __float_as_int(x), 0x130, 0xF, 0xF, true));
}

// Fully wave-independent body: no LDS, no __syncthreads. Each wave owns
// RWV valid rows; loads RWV+10 rows; iter k computes rows k..RL-1-k, so
// rows 5..RL-6 are exact after 5 iters (ring-validity).
template<bool EDGE>
static __device__ __forceinline__ void dilate_bce(
    const float* __restrict__ hp, const float* __restrict__ op,
    const float* __restrict__ tp, float* __restrict__ partial,
    int tx, int ty, int n, int lane, int wu)
{
    const int x0    = tx * VX - 6;       // even -> 8B-aligned pair loads
    const int gx0   = x0 + 2 * lane;     // this lane's column pair
    const int vy0   = ty * (NW * RWV) + wu * RWV;
    const int ybase = vy0 - 5;           // first loaded row (scalar)

    bool colok = true;
    f32x2 mcol = {1.f, 1.f};
    int gxs = gx0;
    if (EDGE) {
        colok = (gx0 >= 0) & (gx0 < IMG);   // pairs never straddle the edge
        mcol.x = mcol.y = colok ? 1.f : 0.f;
        gxs = colok ? gx0 : 0;              // safe address for masked lanes
    }

    const f32x2 zero = {0.f, 0.f};
    f32x2 h[RL], o[RL];
    #pragma unroll
    for (int r = 0; r < RL; ++r) {
        const int gy = ybase + r;           // scalar -> scalar branch
        if (gy >= 0 && gy < IMG) {
            const size_t idx = (size_t)gy * IMG + gxs;
            f32x2 hv = *(const f32x2*)(hp + idx);
            f32x2 ov = *(const f32x2*)(op + idx);
            h[r] = EDGE ? pk_mul(hv, mcol) : hv;
            o[r] = EDGE ? pk_mul(ov, mcol) : ov;
        } else { h[r] = zero; o[r] = zero; }
    }

    // rows gy==-1 / gy==IMG must be re-zeroed each iteration (zero padding
    // reapplied per conv); they sit at constant indices 4 / RL-5.
    const bool ztop = (ty == 0)         && (wu == 0);
    const bool zbot = (ty == GRIDY - 1) && (wu == NW - 1);

    #pragma unroll
    for (int it = 1; it <= 5; ++it) {
        f32x2 prevH = h[it-1], prevO = o[it-1];
        #pragma unroll
        for (int r = it; r <= RL - 1 - it; ++r) {
            f32x2 cH = h[r], cO = o[r];
            f32x2 vH = pk_add(pk_add(cH, prevH), h[r+1]);   // vertical
            f32x2 vO = pk_add(pk_add(cO, prevO), o[r+1]);
            f32x2 sH = pk_add_swap(vH, cH);                 // in-pair horizontal
            f32x2 sO = pk_add_swap(vO, cO);
            sH.x += dpp_sr1(cH.y); sH.y += dpp_sl1(cH.x);   // cross-pair terms
            sO.x += dpp_sr1(cO.y); sO.y += dpp_sl1(cO.x);
            sH.x = fminf(sH.x, 1.f); sH.y = fminf(sH.y, 1.f);
            sO.x = fminf(sO.x, 1.f); sO.y = fminf(sO.y, 1.f);
            if (EDGE) { sH = pk_mul(sH, mcol); sO = pk_mul(sO, mcol); }
            h[r] = sH; o[r] = sO;
            prevH = cH; prevO = cO;
        }
        if (ztop) { h[4]    = zero; o[4]    = zero; }
        if (zbot) { h[RL-5] = zero; o[RL-5] = zero; }
    }

    // ---- BCE on rows 5..RL-6 (gy in-image by construction), lanes 3..60.
    // log2-space accumulate; finalize scales by ln2.
    const float C = -144.26950408889634f;   // -100 / ln2
    float psum = 0.f;
    bool lane_ok = (lane >= 3) & (lane <= 60);
    if (EDGE) lane_ok = lane_ok & colok;
    if (lane_ok) {
        #pragma unroll
        for (int r = 5; r <= RL - 6; ++r) {
            const int gy = ybase + r;
            f32x2 p = pk_mul(h[r], o[r]);
            f32x2 t = *(const f32x2*)(tp + (size_t)gy * IMG + gx0);
            float lp0  = fmaxf(__log2f(p.x),       C);
            float l1p0 = fmaxf(__log2f(1.f - p.x), C);
            float lp1  = fmaxf(__log2f(p.y),       C);
            float l1p1 = fmaxf(__log2f(1.f - p.y), C);
            psum += t.x * lp0 + (1.f - t.x) * l1p0;
            psum += t.y * lp1 + (1.f - t.y) * l1p1;
        }
    }

    #pragma unroll
    for (int off = 32; off > 0; off >>= 1)
        psum += __shfl_down(psum, off, 64);
    if (lane == 0)
        partial[(((size_t)n * GRIDY + ty) * GRIDX + tx) * NW + wu] = psum;
}

// (256,4): 128-VGPR budget; working set ~88 (arrays) + temps -> no spill.
// 4 waves/SIMD occupancy, but ZERO barriers: waves never wait on each other.
__global__ __launch_bounds__(256, 4) void boundary_bce_fused(
    const float* __restrict__ hand,
    const float* __restrict__ obj,
    const float* __restrict__ target,
    float* __restrict__ partial)
{
    const int tid  = threadIdx.x;
    const int lane = tid & 63;
    const int wu   = __builtin_amdgcn_readfirstlane(tid >> 6);  // scalar wave id
    const int tx = blockIdx.x, ty = blockIdx.y, n = blockIdx.z;

    const size_t ioff = (size_t)n * IMG * IMG;
    const float* hp = hand   + ioff;
    const float* op = obj    + ioff;
    const float* tp = target + ioff;

    if (tx == 0 || tx == GRIDX - 1)
        dilate_bce<true >(hp, op, tp, partial, tx, ty, n, lane, wu);
    else
        dilate_bce<false>(hp, op, tp, partial, tx, ty, n, lane, wu);
}

__global__ __launch_bounds__(256) void boundary_bce_finalize(
    const float* __restrict__ partial, float* __restrict__ out)
{
    float s = 0.f;
    for (int i = threadIdx.x; i < NPART; i += 256) s += partial[i];
    #pragma unroll
    for (int off = 32; off > 0; off >>= 1)
        s += __shfl_down(s, off, 64);
    __shared__ float ws[4];
    if ((threadIdx.x & 63) == 0) ws[threadIdx.x >> 6] = s;
    __syncthreads();
    if (threadIdx.x == 0) {
        const float LN2 = 0.69314718055994531f;
        float tot = ws[0] + ws[1] + ws[2] + ws[3];
        out[0] = -(tot * LN2) / (float)((size_t)NIMG * IMG * IMG);
    }
}

extern "C" void kernel_launch(void* const* d_in, const int* in_sizes, int n_in,
                              void* d_out, int out_size, void* d_ws, size_t ws_size,
                              hipStream_t stream)
{
    const float* hand   = (const float*)d_in[0];
    const float* obj    = (const float*)d_in[1];
    const float* target = (const float*)d_in[2];
    float* partial = (float*)d_ws;   // NPART floats, every slot written each call

    dim3 grid(GRIDX, GRIDY, NIMG);   // 4 x 8 x 64 = 2048 blocks, 4 indep waves each
    boundary_bce_fused<<<grid, 256, 0, stream>>>(hand, obj, target, partial);
    boundary_bce_finalize<<<1, 256, 0, stream>>>(partial, (float*)d_out);
}

// Round 7
// 144.482 us; speedup vs baseline: 1.1065x; 1.1065x over previous
//
#include <hip/hip_runtime.h>

#define IMG   384
#define NIMG  64
#define NW    8                 // waves per block (vertical strips)
#define RW    4                 // rows per wave (register columns)
#define TH    (NW*RW)           // 32 tile rows
#define VY    (TH - 10)         // 22 valid rows per tile
#define VX    116               // valid cols per tile
#define GRIDX 4                 // 3*116 + 36 = 384
#define GRIDY 18                // 18*22 = 396 >= 384
#define NPART (GRIDX*GRIDY*NIMG)   // 4608 block partials

typedef float f32x2 __attribute__((ext_vector_type(2)));

static __device__ __forceinline__ f32x2 pk_add(f32x2 a, f32x2 b) {
    f32x2 d; asm("v_pk_add_f32 %0, %1, %2" : "=v"(d) : "v"(a), "v"(b)); return d;
}
// d.lo = a.lo + b.hi ; d.hi = a.hi + b.lo   (within-pair horizontal terms)
static __device__ __forceinline__ f32x2 pk_add_swap(f32x2 a, f32x2 b) {
    f32x2 d; asm("v_pk_add_f32 %0, %1, %2 op_sel:[0,1] op_sel_hi:[1,0]"
                 : "=v"(d) : "v"(a), "v"(b)); return d;
}
static __device__ __forceinline__ f32x2 pk_mul(f32x2 a, f32x2 b) {
    f32x2 d; asm("v_pk_mul_f32 %0, %1, %2" : "=v"(d) : "v"(a), "v"(b)); return d;
}
// lane i <- lane i-1, lane 0 gets 0 (WAVE_SHR1)
static __device__ __forceinline__ float dpp_sr1(float x) {
    return __int_as_float(
        __builtin_amdgcn_update_dpp(0, __float_as_int(x), 0x138, 0xF, 0xF, true));
}
// lane i <- lane i+1, lane 63 gets 0 (WAVE_SHL1)
static __device__ __forceinline__ float dpp_sl1(float x) {
    return __int_as_float(
        __builtin_amdgcn_update_dpp(0, __float_as_int(x), 0x130, 0xF, 0xF, true));
}

// (512, 8): 8 waves/EU -> 4 blocks/CU, 64-VGPR budget. Arrays are only
// h[4]+o[4] = 16 VGPRs (round 4's spill was 40 + temps; this fits).
__global__ __launch_bounds__(512, 8) void boundary_bce_fused(
    const float* __restrict__ hand,
    const float* __restrict__ obj,
    const float* __restrict__ target,
    float* __restrict__ partial)
{
    const int tid  = threadIdx.x;
    const int lane = tid & 63;
    const int wu   = __builtin_amdgcn_readfirstlane(tid >> 6);  // scalar wave id
    const int tx = blockIdx.x, ty = blockIdx.y, n = blockIdx.z;

    const int x0    = tx * VX - 6;          // even -> 8B-aligned pair loads
    const int y0    = ty * VY - 5;
    const int gx0   = x0 + 2 * lane;        // this lane's column pair
    const int ybase = y0 + wu * RW;         // scalar

    const size_t ioff = (size_t)n * IMG * IMG;
    const float* __restrict__ hp = hand   + ioff;
    const float* __restrict__ op = obj    + ioff;
    const float* __restrict__ tp = target + ioff;

    // IMG even & gx0 even => a pair is fully in-image or fully out.
    const bool colok = (gx0 >= 0) & (gx0 < IMG);
    const float mc   = colok ? 1.f : 0.f;
    const f32x2 mcol = {mc, mc};
    const f32x2 zero = {0.f, 0.f};

    __shared__ int s_go;                    // block-wide AND of wave flags
    __shared__ f32x2 sTH[2][NW][64], sBH[2][NW][64];
    __shared__ f32x2 sTO[2][NW][64], sBO[2][NW][64];
    if (tid == 0) s_go = 1;                 // ordered by the iter-0 barrier

    f32x2 h[RW], o[RW];
    #pragma unroll
    for (int r = 0; r < RW; ++r) {
        const int gy = ybase + r;           // wave-uniform -> scalar branch
        if (gy >= 0 && gy < IMG) {
            const size_t idx = (size_t)gy * IMG + gx0;
            h[r] = colok ? *(const f32x2*)(hp + idx) : zero;
            o[r] = colok ? *(const f32x2*)(op + idx) : zero;
        } else { h[r] = zero; o[r] = zero; }
    }

    // rows gy==-1 / gy==IMG re-zeroed each iter (zero padding reapplied per
    // conv). Constant indices: ty==0: gy=-1 -> wu==1,r==0 (ybase=-1).
    //                          ty==17: gy=384 -> wu==3,r==3 (ybase=381).
    const bool ztop = (ty == 0)         && (wu == 1);
    const bool zbot = (ty == GRIDY - 1) && (wu == 3);

    #define DILATE_ITER(b)                                                   \
    {                                                                        \
        sTH[b][wu][lane] = h[0];  sBH[b][wu][lane] = h[RW-1];                \
        sTO[b][wu][lane] = o[0];  sBO[b][wu][lane] = o[RW-1];                \
        __syncthreads();                                                     \
        f32x2 upH = (wu > 0)      ? sBH[b][wu-1][lane] : zero;               \
        f32x2 upO = (wu > 0)      ? sBO[b][wu-1][lane] : zero;               \
        f32x2 dnH = (wu < NW - 1) ? sTH[b][wu+1][lane] : zero;               \
        f32x2 dnO = (wu < NW - 1) ? sTO[b][wu+1][lane] : zero;               \
        f32x2 prevH = upH, prevO = upO;                                      \
        _Pragma("unroll")                                                    \
        for (int r = 0; r < RW; ++r) {                                       \
            f32x2 belowH = (r == RW - 1) ? dnH : h[r+1];                     \
            f32x2 belowO = (r == RW - 1) ? dnO : o[r+1];                     \
            f32x2 cH = h[r], cO = o[r];                                      \
            f32x2 vH = pk_add(pk_add(cH, prevH), belowH);                    \
            f32x2 vO = pk_add(pk_add(cO, prevO), belowO);                    \
            f32x2 sH = pk_add_swap(vH, cH);                                  \
            f32x2 sO = pk_add_swap(vO, cO);                                  \
            sH.x += dpp_sr1(cH.y); sH.y += dpp_sl1(cH.x);                    \
            sO.x += dpp_sr1(cO.y); sO.y += dpp_sl1(cO.x);                    \
            sH.x = fminf(sH.x, 1.f); sH.y = fminf(sH.y, 1.f);                \
            sO.x = fminf(sO.x, 1.f); sO.y = fminf(sO.y, 1.f);                \
            h[r] = pk_mul(sH, mcol);                                         \
            o[r] = pk_mul(sO, mcol);                                         \
            prevH = cH; prevO = cO;                                          \
        }                                                                    \
        if (ztop) { h[0] = zero; o[0] = zero; }                              \
        if (zbot) { h[3] = zero; o[3] = zero; }                              \
    }

    DILATE_ITER(0)
    DILATE_ITER(1)

    // ---- saturation check over this wave's BCE-read cells ----
    // Dilation is extensive (out >= in, clamp at 1): a cell at 1.0 stays 1.0
    // through all remaining iterations regardless of neighbors. If every
    // BCE-read cell (both masks) is exactly 1.0 after 2 iters, iterations
    // 3-5 cannot change them -> skip, and BCE collapses to C*sum(1-t).
    float mm = 1.f;
    #pragma unroll
    for (int r = 0; r < RW; ++r) {
        const int trow = wu * RW + r;       // scalar
        const int gy   = ybase + r;
        if (trow >= 5 && trow <= TH - 6 && gy < IMG)
            mm = fminf(mm, fminf(fminf(h[r].x, h[r].y), fminf(o[r].x, o[r].y)));
    }
    const bool laneok = colok & (lane >= 3) & (lane <= 60);
    mm = laneok ? mm : 1.f;
    const unsigned long long bal = __ballot(mm == 1.0f);
    if (lane == 0 && bal != ~0ull) s_go = 0;    // benign same-value race
    __syncthreads();                             // also orders iter-2 publish

    const float C = -144.26950408889634f;   // -100 / ln2 (log2-space accum)
    float psum = 0.f;

    if (s_go) {                             // block-uniform fast path: p == 1
        if (laneok) {
            #pragma unroll
            for (int r = 0; r < RW; ++r) {
                const int trow = wu * RW + r;
                const int gy   = ybase + r;
                if (trow >= 5 && trow <= TH - 6 && gy < IMG) {
                    f32x2 t = *(const f32x2*)(tp + (size_t)gy * IMG + gx0);
                    psum += (1.f - t.x) + (1.f - t.y);
                }
            }
            psum *= C;
        }
    } else {                                // full iterations 3-5 + exact BCE
        DILATE_ITER(0)
        __syncthreads();                    // protect buffer 1 reuse
        DILATE_ITER(1)
        __syncthreads();
        DILATE_ITER(0)
        if (laneok) {
            #pragma unroll
            for (int r = 0; r < RW; ++r) {
                const int trow = wu * RW + r;
                const int gy   = ybase + r;
                if (trow >= 5 && trow <= TH - 6 && gy < IMG) {
                    f32x2 p = pk_mul(h[r], o[r]);
                    f32x2 t = *(const f32x2*)(tp + (size_t)gy * IMG + gx0);
                    float lp0  = fmaxf(__log2f(p.x),       C);
                    float l1p0 = fmaxf(__log2f(1.f - p.x), C);
                    float lp1  = fmaxf(__log2f(p.y),       C);
                    float l1p1 = fmaxf(__log2f(1.f - p.y), C);
                    psum += t.x * lp0 + (1.f - t.x) * l1p0;
                    psum += t.y * lp1 + (1.f - t.y) * l1p1;
                }
            }
        }
    }
    #undef DILATE_ITER

    // block reduction -> one partial per block
    #pragma unroll
    for (int off = 32; off > 0; off >>= 1)
        psum += __shfl_down(psum, off, 64);
    __shared__ float wsum[NW];
    if (lane == 0) wsum[wu] = psum;
    __syncthreads();
    if (tid == 0) {
        float s = 0.f;
        #pragma unroll
        for (int i = 0; i < NW; ++i) s += wsum[i];
        partial[(((size_t)n * GRIDY + ty) * GRIDX + tx)] = s;
    }
}

__global__ __launch_bounds__(256) void boundary_bce_finalize(
    const float* __restrict__ partial, float* __restrict__ out)
{
    float s = 0.f;
    for (int i = threadIdx.x; i < NPART; i += 256) s += partial[i];
    #pragma unroll
    for (int off = 32; off > 0; off >>= 1)
        s += __shfl_down(s, off, 64);
    __shared__ float ws[4];
    if ((threadIdx.x & 63) == 0) ws[threadIdx.x >> 6] = s;
    __syncthreads();
    if (threadIdx.x == 0) {
        const float LN2 = 0.69314718055994531f;
        float tot = ws[0] + ws[1] + ws[2] + ws[3];
        out[0] = -(tot * LN2) / (float)((size_t)NIMG * IMG * IMG);
    }
}

extern "C" void kernel_launch(void* const* d_in, const int* in_sizes, int n_in,
                              void* d_out, int out_size, void* d_ws, size_t ws_size,
                              hipStream_t stream)
{
    const float* hand   = (const float*)d_in[0];
    const float* obj    = (const float*)d_in[1];
    const float* target = (const float*)d_in[2];
    float* partial = (float*)d_ws;   // NPART floats, every slot written each call

    dim3 grid(GRIDX, GRIDY, NIMG);   // 4 x 18 x 64 = 4608 blocks, 512 threads
    boundary_bce_fused<<<grid, 512, 0, stream>>>(hand, obj, target, partial);
    boundary_bce_finalize<<<1, 256, 0, stream>>>(partial, (float*)d_out);
}